// Round 1
// baseline (5312.871 us; speedup 1.0000x reference)
//
#include <hip/hip_runtime.h>
#include <hip/hip_bf16.h>

#define Bb 16
#define Ls 2048
#define Dd 64
#define QT 16
#define NT 512
#define NW 8

typedef __attribute__((ext_vector_type(8))) short short8;
typedef __attribute__((ext_vector_type(4))) float f32x4;

__device__ __forceinline__ unsigned short f2bf(float f) {
  unsigned int u = __float_as_uint(f);
  u += 0x7fffu + ((u >> 16) & 1u);
  return (unsigned short)(u >> 16);
}
__device__ __forceinline__ float bf2f(unsigned short h) {
  return __uint_as_float(((unsigned int)h) << 16);
}
// block-of-8 XOR swizzle on the k index so MFMA A-frag ds_read_b128
// (16 lanes reading 16 different rows at the same k) is conflict-free
__device__ __forceinline__ int swz(int row, int kk) {
  return (((kk >> 3) ^ (row & 7)) << 3) | (kk & 7);
}

__global__ __launch_bounds__(NT)
void sdpa_dot_kernel(const float* __restrict__ qg, const float* __restrict__ kg,
                     const float* __restrict__ vg, const int* __restrict__ mg,
                     float* __restrict__ outO, float* __restrict__ outA)
{
  __shared__ unsigned short Sl[QT][Ls];   // 64 KB: masked scores, bf16, swizzled
  __shared__ float Qs[QT][Dd];            // 4 KB
  __shared__ float red[NW][QT];           // row-sum partials per wave
  __shared__ float dinv[QT];
  __shared__ float Ored[4][16][17];       // PV cross-half reduce, padded

  const int tid  = threadIdx.x;
  const int lane = tid & 63;
  const int w    = tid >> 6;
  const int bid  = blockIdx.x;
  const int b    = bid >> 7;              // batch
  const int q0   = (bid & 127) * QT;      // q-row base

  // ---- Phase 0: Q tile -> LDS
  for (int i = tid; i < QT * Dd; i += NT) {
    int r = i >> 6, c = i & 63;
    Qs[r][c] = qg[((size_t)(b * Ls + q0 + r)) * Dd + c];
  }
  __syncthreads();

  // ---- Phase 1: fp32 QK^T + mask + fp32 row-sum partials, S -> LDS as bf16
  float rs[QT];
#pragma unroll
  for (int qt = 0; qt < QT; ++qt) rs[qt] = 0.f;

  for (int j = 0; j < Ls / NT; ++j) {
    int kk = j * NT + tid;               // this thread's k column
    const f32x4* kp = (const f32x4*)(kg + ((size_t)(b * Ls + kk)) * Dd);
    f32x4 kr[16];
#pragma unroll
    for (int d4 = 0; d4 < 16; ++d4) kr[d4] = kp[d4];
    const int* mrow = mg + (size_t)(b * Ls + q0) * Ls + kk;  // +qt*Ls per row
#pragma unroll
    for (int qt = 0; qt < QT; ++qt) {
      const f32x4* qp = (const f32x4*)Qs[qt];   // uniform addr -> LDS broadcast
      float acc = 0.f;
#pragma unroll
      for (int d4 = 0; d4 < 16; ++d4) {
        f32x4 qv = qp[d4];
        f32x4 kv = kr[d4];
        acc += qv.x * kv.x;
        acc += qv.y * kv.y;
        acc += qv.z * kv.z;
        acc += qv.w * kv.w;
      }
      int m = mrow[qt * Ls];             // nonzero (int 1 or 1.0f bits) = masked
      acc = m ? 0.f : acc;
      rs[qt] += acc;
      // pack lane-pairs so LDS writes are b32 (no same-dword byte writes)
      float accn = __shfl_down(acc, 1);
      if (!(lane & 1)) {
        unsigned int pk = (unsigned int)f2bf(acc) | ((unsigned int)f2bf(accn) << 16);
        *(unsigned int*)&Sl[qt][swz(qt, kk)] = pk;
      }
    }
  }

  // ---- Phase 2: denom = clamp(rowsum, 1e-14); dinv = 1/denom
#pragma unroll
  for (int qt = 0; qt < QT; ++qt) {
    float x = rs[qt];
#pragma unroll
    for (int off = 32; off > 0; off >>= 1) x += __shfl_down(x, off);
    if (lane == 0) red[w][qt] = x;
  }
  __syncthreads();
  if (tid < QT) {
    float s = 0.f;
#pragma unroll
    for (int ww = 0; ww < NW; ++ww) s += red[ww][tid];
    s = fmaxf(s, 1e-14f);
    dinv[tid] = 1.0f / s;
  }
  __syncthreads();

  // ---- Phase 3b: O = (S_bf16 . V_bf16) * dinv via MFMA 16x16x32
  {
    const int n0    = (w & 3) * 16;   // output col tile
    const int khalf = w >> 2;         // k range half
    const int colD  = lane & 15;      // A row / B col / D col
    const int quad  = lane >> 4;      // k sub-group
    f32x4 acc = {0.f, 0.f, 0.f, 0.f};
    for (int ks = 0; ks < 32; ++ks) {
      int k0 = (khalf * 32 + ks) * 32 + quad * 8;
      short8 af = *(const short8*)&Sl[colD][swz(colD, k0)];
      const float* vp = vg + ((size_t)(b * Ls + k0)) * Dd + n0 + colD;
      short8 bf;
#pragma unroll
      for (int jj = 0; jj < 8; ++jj) bf[jj] = (short)f2bf(vp[jj * Dd]);
      acc = __builtin_amdgcn_mfma_f32_16x16x32_bf16(af, bf, acc, 0, 0, 0);
    }
    if (w >= 4) {
#pragma unroll
      for (int r = 0; r < 4; ++r) Ored[w - 4][quad * 4 + r][colD] = acc[r];
    }
    __syncthreads();
    if (w < 4) {
#pragma unroll
      for (int r = 0; r < 4; ++r) {
        int orow = quad * 4 + r;
        float val = (acc[r] + Ored[w][orow][colD]) * dinv[orow];
        outO[((size_t)(b * Ls + q0 + orow)) * Dd + n0 + colD] = val;
      }
    }
  }

  // ---- Phase 3a: attn = bf16(S) * dinv, coalesced stores
  {
    float dv[QT];
#pragma unroll
    for (int qt = 0; qt < QT; ++qt) dv[qt] = dinv[qt];
    for (int j = 0; j < Ls / NT; ++j) {
      int kk = j * NT + tid;
#pragma unroll
      for (int qt = 0; qt < QT; ++qt) {
        float a = bf2f(Sl[qt][swz(qt, kk)]) * dv[qt];
        outA[(size_t)(b * Ls + q0 + qt) * Ls + kk] = a;
      }
    }
  }
}

extern "C" void kernel_launch(void* const* d_in, const int* in_sizes, int n_in,
                              void* d_out, int out_size, void* d_ws, size_t ws_size,
                              hipStream_t stream) {
  const float* q = (const float*)d_in[0];
  const float* k = (const float*)d_in[1];
  const float* v = (const float*)d_in[2];
  const int*   m = (const int*)d_in[3];
  float* outO = (float*)d_out;
  float* outA = outO + (size_t)Bb * Ls * Dd;
  dim3 grid(Bb * (Ls / QT));
  sdpa_dot_kernel<<<grid, NT, 0, stream>>>(q, k, v, m, outO, outA);
}

// Round 2
// 342.731 us; speedup vs baseline: 15.5016x; 15.5016x over previous
//
#include <hip/hip_runtime.h>
#include <hip/hip_bf16.h>

#define Bb 16
#define Ls 2048
#define Dd 64
#define QT 16
#define NT 512
#define NW 8

typedef __attribute__((ext_vector_type(8))) short short8;
typedef __attribute__((ext_vector_type(4))) float f32x4;

__device__ __forceinline__ unsigned short f2bf(float f) {
  unsigned int u = __float_as_uint(f);
  u += 0x7fffu + ((u >> 16) & 1u);
  return (unsigned short)(u >> 16);
}
__device__ __forceinline__ float bf2f(unsigned short h) {
  return __uint_as_float(((unsigned int)h) << 16);
}
// block-of-8 XOR swizzle on the k index so MFMA A-frag ds_read_b128
// (16 lanes reading 16 different rows at the same k) is 2-way (free)
__device__ __forceinline__ int swz(int row, int kk) {
  return (((kk >> 3) ^ (row & 7)) << 3) | (kk & 7);
}

__global__ __launch_bounds__(NT)
void sdpa_dot_kernel(const float* __restrict__ qg, const float* __restrict__ kg,
                     const float* __restrict__ vg, const int* __restrict__ mg,
                     float* __restrict__ outO, float* __restrict__ outA)
{
  __shared__ unsigned short Sl[QT][Ls];   // 64 KB: masked scores, bf16, swizzled
  __shared__ float Qs[QT][Dd];            // 4 KB
  __shared__ float red[NW][QT];           // row-sum partials per wave
  __shared__ float dinv[QT];
  __shared__ float Ored[4][16][17];       // PV cross-half reduce, padded

  const int tid  = threadIdx.x;
  const int lane = tid & 63;
  const int w    = tid >> 6;
  // XCD-aware bijective swizzle (2048 blocks % 8 == 0): each XCD gets a
  // contiguous 256-block chunk -> only 2 batches' K/V per XCD L2.
  const int bid  = (int)(blockIdx.x % 8) * 256 + (int)(blockIdx.x / 8);
  const int b    = bid >> 7;              // batch
  const int q0   = (bid & 127) * QT;      // q-row base

  // ---- Phase 0: Q tile -> LDS
  for (int i = tid; i < QT * Dd; i += NT) {
    int r = i >> 6, c = i & 63;
    Qs[r][c] = qg[((size_t)(b * Ls + q0 + r)) * Dd + c];
  }
  __syncthreads();

  // ---- Phase 1: fp32 QK^T + mask + fp32 row-sum partials, S -> LDS as bf16
  // Each thread owns 2 ADJACENT k-columns (kk, kk+1); D split into 4 chunks
  // of 16 dims to keep live VGPRs ~100 (R0 spilled: 11.7 GB scratch traffic).
  float rs[QT];
#pragma unroll
  for (int qt = 0; qt < QT; ++qt) rs[qt] = 0.f;

#pragma unroll 1
  for (int j = 0; j < 2; ++j) {
    const int kk = j * 1024 + 2 * tid;
    const f32x4* kp = (const f32x4*)(kg + ((size_t)(b * Ls + kk)) * Dd);
    float acc0[QT], acc1[QT];
#pragma unroll
    for (int qt = 0; qt < QT; ++qt) { acc0[qt] = 0.f; acc1[qt] = 0.f; }

#pragma unroll 1
    for (int c = 0; c < 4; ++c) {
      f32x4 k0[4], k1[4];
#pragma unroll
      for (int t = 0; t < 4; ++t) {
        k0[t] = kp[c * 4 + t];        // row kk,   dims c*16..c*16+15
        k1[t] = kp[16 + c * 4 + t];   // row kk+1, dims c*16..c*16+15
      }
#pragma unroll
      for (int qt = 0; qt < QT; ++qt) {
        const f32x4* qp = (const f32x4*)&Qs[qt][c * 16];  // uniform -> broadcast
#pragma unroll
        for (int t = 0; t < 4; ++t) {
          f32x4 qv = qp[t];
          acc0[qt] += qv.x * k0[t].x; acc0[qt] += qv.y * k0[t].y;
          acc0[qt] += qv.z * k0[t].z; acc0[qt] += qv.w * k0[t].w;
          acc1[qt] += qv.x * k1[t].x; acc1[qt] += qv.y * k1[t].y;
          acc1[qt] += qv.z * k1[t].z; acc1[qt] += qv.w * k1[t].w;
        }
      }
    }

    const int* mrow = mg + (size_t)(b * Ls + q0) * Ls + kk;
#pragma unroll
    for (int qt = 0; qt < QT; ++qt) {
      int2 mm = *(const int2*)&mrow[qt * Ls];   // 8B-aligned (kk even)
      float a0 = mm.x ? 0.f : acc0[qt];
      float a1 = mm.y ? 0.f : acc1[qt];
      rs[qt] += a0 + a1;
      unsigned int pk = (unsigned int)f2bf(a0) | ((unsigned int)f2bf(a1) << 16);
      *(unsigned int*)&Sl[qt][swz(qt, kk)] = pk;  // pair stays adjacent in swz
    }
  }

  // ---- Phase 2: denom = clamp(rowsum, 1e-14); dinv = 1/denom
#pragma unroll
  for (int qt = 0; qt < QT; ++qt) {
    float x = rs[qt];
#pragma unroll
    for (int off = 32; off > 0; off >>= 1) x += __shfl_down(x, off);
    if (lane == 0) red[w][qt] = x;
  }
  __syncthreads();
  if (tid < QT) {
    float s = 0.f;
#pragma unroll
    for (int ww = 0; ww < NW; ++ww) s += red[ww][tid];
    s = fmaxf(s, 1e-14f);
    dinv[tid] = 1.0f / s;
  }
  __syncthreads();

  // ---- Phase 3a: attn = bf16(S) * dinv, float2 coalesced stores (issue the
  // big HBM writes first; they are fire-and-forget and overlap phase 3b)
  {
#pragma unroll 1
    for (int j = 0; j < 2; ++j) {
      const int kk = j * 1024 + 2 * tid;
#pragma unroll
      for (int qt = 0; qt < QT; ++qt) {
        unsigned int pk = *(const unsigned int*)&Sl[qt][swz(qt, kk)];
        float2 st;
        st.x = bf2f((unsigned short)(pk & 0xffffu)) * dinv[qt];
        st.y = bf2f((unsigned short)(pk >> 16)) * dinv[qt];
        *(float2*)&outA[(size_t)(b * Ls + q0 + qt) * Ls + kk] = st;
      }
    }
  }

  // ---- Phase 3b: O = (S_bf16 . V_bf16) * dinv via MFMA 16x16x32
  {
    const int n0    = (w & 3) * 16;   // output col tile
    const int khalf = w >> 2;         // k range half
    const int colD  = lane & 15;      // A row / B col / D col
    const int quad  = lane >> 4;      // k sub-group
    f32x4 acc = {0.f, 0.f, 0.f, 0.f};
    for (int ks = 0; ks < 32; ++ks) {
      int k0 = (khalf * 32 + ks) * 32 + quad * 8;
      short8 af = *(const short8*)&Sl[colD][swz(colD, k0)];
      const float* vp = vg + ((size_t)(b * Ls + k0)) * Dd + n0 + colD;
      short8 bf;
#pragma unroll
      for (int jj = 0; jj < 8; ++jj) bf[jj] = (short)f2bf(vp[jj * Dd]);
      acc = __builtin_amdgcn_mfma_f32_16x16x32_bf16(af, bf, acc, 0, 0, 0);
    }
    if (w >= 4) {
#pragma unroll
      for (int r = 0; r < 4; ++r) Ored[w - 4][quad * 4 + r][colD] = acc[r];
    }
    __syncthreads();
    if (w < 4) {
#pragma unroll
      for (int r = 0; r < 4; ++r) {
        int orow = quad * 4 + r;
        float val = (acc[r] + Ored[w][orow][colD]) * dinv[orow];
        outO[((size_t)(b * Ls + q0 + orow)) * Dd + n0 + colD] = val;
      }
    }
  }
}

extern "C" void kernel_launch(void* const* d_in, const int* in_sizes, int n_in,
                              void* d_out, int out_size, void* d_ws, size_t ws_size,
                              hipStream_t stream) {
  const float* q = (const float*)d_in[0];
  const float* k = (const float*)d_in[1];
  const float* v = (const float*)d_in[2];
  const int*   m = (const int*)d_in[3];
  float* outO = (float*)d_out;
  float* outA = outO + (size_t)Bb * Ls * Dd;
  dim3 grid(Bb * (Ls / QT));
  sdpa_dot_kernel<<<grid, NT, 0, stream>>>(q, k, v, m, outO, outA);
}

// Round 3
// 281.678 us; speedup vs baseline: 18.8615x; 1.2167x over previous
//
#include <hip/hip_runtime.h>

#define Bb 16
#define Lq 2048
#define Dd 64
#define QT 16        // q-rows per block
#define NT 512
#define NWAVE 8
#define KCH 256      // k-cols per wave
#define QPAD 72      // u16 row stride for Q split planes (72*2B=144B: 16B-aligned, 2-way banks)

typedef __attribute__((ext_vector_type(8))) short short8;
typedef __attribute__((ext_vector_type(4))) float f32x4;
typedef __attribute__((ext_vector_type(2))) float f32x2;
typedef __attribute__((ext_vector_type(4))) unsigned int u32x4;
typedef __attribute__((ext_vector_type(4))) int i32x4;

__device__ __forceinline__ unsigned int f2bf1(float f) {       // RNE bf16, in low16
  unsigned int u = __float_as_uint(f);
  return (u + 0x7fffu + ((u >> 16) & 1u)) >> 16;
}
__device__ __forceinline__ unsigned int prne(float a, float b) { // pack RNE pair
  return f2bf1(a) | (f2bf1(b) << 16);
}
__device__ __forceinline__ float bf_rne(float f) {             // RNE-round to bf16, as f32
  unsigned int u = __float_as_uint(f);
  u = (u + 0x7fffu + ((u >> 16) & 1u)) & 0xFFFF0000u;
  return __uint_as_float(u);
}
__device__ __forceinline__ float btrunc(float f) {             // RTZ bf16, as f32
  return __uint_as_float(__float_as_uint(f) & 0xFFFF0000u);
}
// pack top16 of two f32 (already bf16-exact) into one u32: low=a, high=b
__device__ __forceinline__ unsigned int bpk(float a, float b) {
  return __builtin_amdgcn_perm(__float_as_uint(b), __float_as_uint(a), 0x07060302);
}
__device__ __forceinline__ f32x4 MF(u32x4 a, u32x4 b, f32x4 c) {
  return __builtin_amdgcn_mfma_f32_16x16x32_bf16(
      __builtin_bit_cast(short8, a), __builtin_bit_cast(short8, b), c, 0, 0, 0);
}

struct Sp3 { u32x4 h, m, l; };
// split 8 consecutive-k f32 into 3 packed-bf16 fragment words (exact: x=h+m+l+O(2^-22))
__device__ __forceinline__ Sp3 split8(f32x4 a, f32x4 b) {
  float e[8] = {a.x, a.y, a.z, a.w, b.x, b.y, b.z, b.w};
  float hf[8], mf[8], lf[8];
#pragma unroll
  for (int i = 0; i < 8; ++i) {
    float h = bf_rne(e[i]);
    float r1 = e[i] - h;
    float m = btrunc(r1);
    float r2 = r1 - m;
    hf[i] = h; mf[i] = m; lf[i] = btrunc(r2);
  }
  Sp3 s;
#pragma unroll
  for (int i = 0; i < 4; ++i) {
    s.h[i] = bpk(hf[2 * i], hf[2 * i + 1]);
    s.m[i] = bpk(mf[2 * i], mf[2 * i + 1]);
    s.l[i] = bpk(lf[2 * i], lf[2 * i + 1]);
  }
  return s;
}

__global__ __launch_bounds__(NT, 4)
void sdpa_dot_kernel(const float* __restrict__ qg, const float* __restrict__ kg,
                     const float* __restrict__ vg, const int* __restrict__ mg,
                     float* __restrict__ outO, float* __restrict__ outA)
{
  __shared__ unsigned short Qh[QT][QPAD], Qm[QT][QPAD], Ql[QT][QPAD]; // 6.9 KB
  __shared__ float red[QT][NWAVE];                                    // 512 B
  __shared__ float dinv_s[QT];
  __shared__ float Ored[NWAVE][QT][Dd];                               // 32 KB

  const int tid = threadIdx.x;
  const int l   = tid & 63;
  const int ln  = l & 15;          // 16-group index
  const int u   = l >> 4;          // quad
  const int w   = tid >> 6;        // wave
  // XCD-aware bijective swizzle (2048 % 8 == 0)
  const int bid = (int)(blockIdx.x % 8) * 256 + (int)(blockIdx.x / 8);
  const int b   = bid >> 7;
  const int q0  = (bid & 127) * QT;
  const int kb  = w * KCH;

  // ---- Phase 0: load Q tile, 3-way bf16 split -> LDS planes
  {
    int r = tid >> 5, c = (tid & 31) * 2;
    f32x2 qv = *(const f32x2*)(qg + (size_t)(b * Lq + q0 + r) * Dd + c);
    float h0 = bf_rne(qv.x), r10 = qv.x - h0;
    float m0 = btrunc(r10),  l0  = btrunc(r10 - m0);
    float h1 = bf_rne(qv.y), r11 = qv.y - h1;
    float m1 = btrunc(r11),  l1  = btrunc(r11 - m1);
    *(unsigned int*)&Qh[r][c] = bpk(h0, h1);
    *(unsigned int*)&Qm[r][c] = bpk(m0, m1);
    *(unsigned int*)&Ql[r][c] = bpk(l0, l1);
  }
  __syncthreads();

  // hoisted Q B-fragments (lane: q-col=ln, dims 32s+8u..+7) — 6 ds_read_b128 total
  u32x4 Bh[2], Bm[2], Bl[2];
#pragma unroll
  for (int s = 0; s < 2; ++s) {
    Bh[s] = *(const u32x4*)&Qh[ln][32 * s + 8 * u];
    Bm[s] = *(const u32x4*)&Qm[ln][32 * s + 8 * u];
    Bl[s] = *(const u32x4*)&Ql[ln][32 * s + 8 * u];
  }

  // ---- Phase 1: S = K.Q^T via 8-term split-bf16 MFMA; mask; row-sum; pack S
  unsigned int su[16][2];
  float rs = 0.f;
#pragma unroll
  for (int t = 0; t < 16; ++t) {
    const float* kr = kg + (size_t)(b * Lq + kb + 16 * t + ln) * Dd + 8 * u;
    f32x4 acc = {0.f, 0.f, 0.f, 0.f};
#pragma unroll
    for (int s = 0; s < 2; ++s) {
      f32x4 k0 = *(const f32x4*)(kr + 32 * s);
      f32x4 k1 = *(const f32x4*)(kr + 32 * s + 4);
      Sp3 A = split8(k0, k1);
      acc = MF(A.h, Bh[s], acc);
      acc = MF(A.h, Bm[s], acc);
      acc = MF(A.m, Bh[s], acc);
      acc = MF(A.m, Bm[s], acc);
      acc = MF(A.h, Bl[s], acc);
      acc = MF(A.l, Bh[s], acc);
      acc = MF(A.m, Bl[s], acc);
      acc = MF(A.l, Bm[s], acc);
    }
    // C layout: lane holds q=ln, kcols kb+16t+4u+{0..3} (reg r)
    const int* mp = mg + (size_t)(b * Lq + q0 + ln) * Lq + kb + 16 * t + 4 * u;
    i32x4 mm4 = *(const i32x4*)mp;
    float s0 = mm4.x ? 0.f : acc.x;
    float s1 = mm4.y ? 0.f : acc.y;
    float s2 = mm4.z ? 0.f : acc.z;
    float s3 = mm4.w ? 0.f : acc.w;
    rs += (s0 + s1) + (s2 + s3);
    su[t][0] = prne(s0, s1);
    su[t][1] = prne(s2, s3);
  }

  // ---- Phase 2: row-sum across quads + waves; per-lane dinv for q=ln
  rs += __shfl_xor(rs, 16);
  rs += __shfl_xor(rs, 32);
  if (l < 16) red[l][w] = rs;
  __syncthreads();
  f32x4 r0 = *(const f32x4*)&red[ln][0];
  f32x4 r1 = *(const f32x4*)&red[ln][4];
  float sum = ((r0.x + r0.y) + (r0.z + r0.w)) + ((r1.x + r1.y) + (r1.z + r1.w));
  float dinv = 1.0f / fmaxf(sum, 1e-14f);
  if (w == 0 && l < 16) dinv_s[l] = dinv;

  // ---- Phase 3: attn stores (fire-and-forget float4, coalesce via quads)
#pragma unroll
  for (int t = 0; t < 16; ++t) {
    float a0 = __uint_as_float(su[t][0] << 16)        * dinv;
    float a1 = __uint_as_float(su[t][0] & 0xFFFF0000u) * dinv;
    float a2 = __uint_as_float(su[t][1] << 16)        * dinv;
    float a3 = __uint_as_float(su[t][1] & 0xFFFF0000u) * dinv;
    f32x4 st = {a0, a1, a2, a3};
    *(f32x4*)(outA + (size_t)(b * Lq + q0 + ln) * Lq + kb + 16 * t + 4 * u) = st;
  }

  // ---- Phase 4: PV over this wave's k-chunk, S straight from registers.
  // A-frag slot (u, j) <- k_off = 16*(j>>2) + 4u + (j&3); V rows match the same map.
  f32x4 pv[4] = {{0,0,0,0},{0,0,0,0},{0,0,0,0},{0,0,0,0}};
#pragma unroll
  for (int g = 0; g < 8; ++g) {
    u32x4 aw = {su[2 * g][0], su[2 * g][1], su[2 * g + 1][0], su[2 * g + 1][1]};
#pragma unroll
    for (int nt = 0; nt < 4; ++nt) {
      const float* vp = vg + (size_t)(b * Lq + kb + 32 * g + 4 * u) * Dd + 16 * nt + ln;
      u32x4 bw;
      bw[0] = prne(vp[0 * Dd],  vp[1 * Dd]);
      bw[1] = prne(vp[2 * Dd],  vp[3 * Dd]);
      bw[2] = prne(vp[16 * Dd], vp[17 * Dd]);
      bw[3] = prne(vp[18 * Dd], vp[19 * Dd]);
      pv[nt] = MF(aw, bw, pv[nt]);
    }
  }

  // ---- Phase 5: cross-wave O reduction + scaled store
#pragma unroll
  for (int nt = 0; nt < 4; ++nt)
#pragma unroll
    for (int r = 0; r < 4; ++r)
      Ored[w][u * 4 + r][nt * 16 + ln] = pv[nt][r];
  __syncthreads();
  {
    int q = tid >> 5, d = (tid & 31) * 2;
    float o0 = 0.f, o1 = 0.f;
#pragma unroll
    for (int ww = 0; ww < NWAVE; ++ww) {
      f32x2 t2 = *(const f32x2*)&Ored[ww][q][d];
      o0 += t2.x; o1 += t2.y;
    }
    float dv = dinv_s[q];
    f32x2 st = {o0 * dv, o1 * dv};
    *(f32x2*)(outO + (size_t)(b * Lq + q0 + q) * Dd + d) = st;
  }
}

extern "C" void kernel_launch(void* const* d_in, const int* in_sizes, int n_in,
                              void* d_out, int out_size, void* d_ws, size_t ws_size,
                              hipStream_t stream) {
  const float* q = (const float*)d_in[0];
  const float* k = (const float*)d_in[1];
  const float* v = (const float*)d_in[2];
  const int*   m = (const int*)d_in[3];
  float* outO = (float*)d_out;
  float* outA = outO + (size_t)Bb * Lq * Dd;
  dim3 grid(Bb * (Lq / QT));
  sdpa_dot_kernel<<<grid, NT, 0, stream>>>(q, k, v, m, outO, outA);
}

// Round 5
// 272.732 us; speedup vs baseline: 19.4802x; 1.0328x over previous
//
#include <hip/hip_runtime.h>

#define Bb 16
#define Lq 2048
#define Dd 64
#define QT 16        // q-rows per block
#define NT 512
#define NWAVE 8
#define KCH 256      // k-cols per wave

typedef _Float16 f16x2 __attribute__((ext_vector_type(2)));
typedef _Float16 f16x8 __attribute__((ext_vector_type(8)));
typedef __attribute__((ext_vector_type(4))) float f32x4;
typedef __attribute__((ext_vector_type(2))) float f32x2;
typedef __attribute__((ext_vector_type(4))) unsigned int u32x4;
typedef __attribute__((ext_vector_type(4))) int i32x4;

union H8 { f16x8 v8; f16x2 h2[4]; unsigned int u[4]; u32x4 u4; };
union H1 { f16x2 h; unsigned int u; };

__device__ __forceinline__ f16x2 pkrtz(float a, float b) {
  return __builtin_bit_cast(f16x2, __builtin_amdgcn_cvt_pkrtz(a, b)); // 1 instr/pair
}
__device__ __forceinline__ f32x4 MF16(f16x8 a, f16x8 b, f32x4 c) {
  return __builtin_amdgcn_mfma_f32_16x16x32_f16(a, b, c, 0, 0, 0);
}

__global__ __launch_bounds__(NT, 4)
void sdpa_dot_kernel(const float* __restrict__ qg, const float* __restrict__ kg,
                     const float* __restrict__ vg, const int* __restrict__ mg,
                     float* __restrict__ outO, float* __restrict__ outA)
{
  __shared__ unsigned int Qh[QT][36], Ql[QT][36];   // packed f16 pairs, 4.6 KB
  __shared__ float red[QT][NWAVE];
  __shared__ float dinv_s[QT];
  __shared__ float Ored[NWAVE][QT][66];             // padded: 2-way banks on store

  const int tid = threadIdx.x;
  const int l   = tid & 63;
  const int ln  = l & 15;
  const int u   = l >> 4;
  const int w   = tid >> 6;
  const int bid = (int)(blockIdx.x % 8) * 256 + (int)(blockIdx.x / 8); // XCD swizzle
  const int b   = bid >> 7;
  const int q0  = (bid & 127) * QT;
  const int kb  = w * KCH;

  // ---- Phase 0: Q tile -> f16 h/l split planes (packed pairs) in LDS
  {
    int r = tid >> 5, d2 = tid & 31;
    f32x2 qv = *(const f32x2*)(qg + (size_t)(b * Lq + q0 + r) * Dd + 2 * d2);
    H1 h, lo;
    h.h = pkrtz(qv.x, qv.y);
    lo.h = pkrtz(qv.x - (float)h.h.x, qv.y - (float)h.h.y);
    Qh[r][d2] = h.u;
    Ql[r][d2] = lo.u;
  }
  __syncthreads();

  // hoisted Q B-fragments: lane (u,ln): col=ln (q), dims 32s+8u..+7
  H8 Bh[2], Bl[2];
#pragma unroll
  for (int s = 0; s < 2; ++s) {
    Bh[s].u4 = *(const u32x4*)&Qh[ln][16 * s + 4 * u];
    Bl[s].u4 = *(const u32x4*)&Ql[ln][16 * s + 4 * u];
  }

  // ---- Phase 1: S = K.Q^T via f16 split (hh+hl+lh); mask; row-sum; pack f16
  unsigned int su[16][2];
  float rs = 0.f;
#pragma unroll
  for (int t = 0; t < 16; ++t) {
    const float* kr = kg + (size_t)(b * Lq + kb + 16 * t + ln) * Dd + 8 * u;
    f32x4 acc = {0.f, 0.f, 0.f, 0.f};
#pragma unroll
    for (int s = 0; s < 2; ++s) {
      f32x4 k0 = *(const f32x4*)(kr + 32 * s);
      f32x4 k1 = *(const f32x4*)(kr + 32 * s + 4);
      H8 H, L;
      H.h2[0] = pkrtz(k0.x, k0.y);
      H.h2[1] = pkrtz(k0.z, k0.w);
      H.h2[2] = pkrtz(k1.x, k1.y);
      H.h2[3] = pkrtz(k1.z, k1.w);
      L.h2[0] = pkrtz(k0.x - (float)H.h2[0].x, k0.y - (float)H.h2[0].y);
      L.h2[1] = pkrtz(k0.z - (float)H.h2[1].x, k0.w - (float)H.h2[1].y);
      L.h2[2] = pkrtz(k1.x - (float)H.h2[2].x, k1.y - (float)H.h2[2].y);
      L.h2[3] = pkrtz(k1.z - (float)H.h2[3].x, k1.w - (float)H.h2[3].y);
      acc = MF16(H.v8, Bh[s].v8, acc);
      acc = MF16(H.v8, Bl[s].v8, acc);
      acc = MF16(L.v8, Bh[s].v8, acc);
    }
    // C layout (HW-verified in R2): lane holds q=ln, k rows kb+16t+4u+{0..3}
    const int* mp = mg + (size_t)(b * Lq + q0 + ln) * Lq + kb + 16 * t + 4 * u;
    i32x4 mm4 = *(const i32x4*)mp;
    float s0 = mm4.x ? 0.f : acc.x;
    float s1 = mm4.y ? 0.f : acc.y;
    float s2 = mm4.z ? 0.f : acc.z;
    float s3 = mm4.w ? 0.f : acc.w;
    rs += (s0 + s1) + (s2 + s3);
    H1 p0, p1;
    p0.h = pkrtz(s0, s1); p1.h = pkrtz(s2, s3);
    su[t][0] = p0.u; su[t][1] = p1.u;
  }

  // ---- Phase 2: row-sum across quads + waves; dinv per q
  rs += __shfl_xor(rs, 16);
  rs += __shfl_xor(rs, 32);
  if (l < 16) red[l][w] = rs;
  __syncthreads();
  f32x4 r0 = *(const f32x4*)&red[ln][0];
  f32x4 r1 = *(const f32x4*)&red[ln][4];
  float sum = ((r0.x + r0.y) + (r0.z + r0.w)) + ((r1.x + r1.y) + (r1.z + r1.w));
  float dinv = 1.0f / fmaxf(sum, 1e-14f);
  if (w == 0 && l < 16) dinv_s[l] = dinv;

  // ---- Phase 3: attn stores first (fire-and-forget, overlaps PV)
#pragma unroll
  for (int t = 0; t < 16; ++t) {
    H1 p0, p1; p0.u = su[t][0]; p1.u = su[t][1];
    f32x4 st = {(float)p0.h.x * dinv, (float)p0.h.y * dinv,
                (float)p1.h.x * dinv, (float)p1.h.y * dinv};
    *(f32x4*)(outA + (size_t)(b * Lq + q0 + ln) * Lq + kb + 16 * t + 4 * u) = st;
  }

  // ---- Phase 4: PV over this wave's k-chunk, S straight from registers (f16)
  // A slot (u,j) <- k_off = 32g + 16*(j>>2) + 4u + (j&3); V rows use same map.
  f32x4 pv[4] = {{0,0,0,0},{0,0,0,0},{0,0,0,0},{0,0,0,0}};
#pragma unroll
  for (int g = 0; g < 8; ++g) {
    H8 aw;
    aw.u[0] = su[2 * g][0];     aw.u[1] = su[2 * g][1];
    aw.u[2] = su[2 * g + 1][0]; aw.u[3] = su[2 * g + 1][1];
    const float* vb = vg + (size_t)(b * Lq + kb + 32 * g + 4 * u) * Dd + ln;
#pragma unroll
    for (int nt = 0; nt < 4; ++nt) {
      const float* vp = vb + 16 * nt;
      H8 bw;
      bw.h2[0] = pkrtz(vp[0],       vp[Dd]);
      bw.h2[1] = pkrtz(vp[2 * Dd],  vp[3 * Dd]);
      bw.h2[2] = pkrtz(vp[16 * Dd], vp[17 * Dd]);
      bw.h2[3] = pkrtz(vp[18 * Dd], vp[19 * Dd]);
      pv[nt] = MF16(aw.v8, bw.v8, pv[nt]);
    }
  }

  // ---- Phase 5: cross-wave O reduction + scaled store
#pragma unroll
  for (int nt = 0; nt < 4; ++nt)
#pragma unroll
    for (int r = 0; r < 4; ++r)
      Ored[w][u * 4 + r][nt * 16 + ln] = pv[nt][r];
  __syncthreads();
  {
    int q = tid >> 5, d = (tid & 31) * 2;
    float o0 = 0.f, o1 = 0.f;
#pragma unroll
    for (int ww = 0; ww < NWAVE; ++ww) {
      o0 += Ored[ww][q][d];
      o1 += Ored[ww][q][d + 1];
    }
    float dv = dinv_s[q];
    f32x2 st = {o0 * dv, o1 * dv};
    *(f32x2*)(outO + (size_t)(b * Lq + q0 + q) * Dd + d) = st;
  }
}

extern "C" void kernel_launch(void* const* d_in, const int* in_sizes, int n_in,
                              void* d_out, int out_size, void* d_ws, size_t ws_size,
                              hipStream_t stream) {
  const float* q = (const float*)d_in[0];
  const float* k = (const float*)d_in[1];
  const float* v = (const float*)d_in[2];
  const int*   m = (const int*)d_in[3];
  float* outO = (float*)d_out;
  float* outA = outO + (size_t)Bb * Lq * Dd;
  dim3 grid(Bb * (Lq / QT));
  sdpa_dot_kernel<<<grid, NT, 0, stream>>>(q, k, v, m, outO, outA);
}